// Round 6
// baseline (10040.461 us; speedup 1.0000x reference)
//
#include <hip/hip_runtime.h>

typedef _Float16 f16;
typedef _Float16 f16x2 __attribute__((ext_vector_type(2)));
typedef _Float16 f16x8 __attribute__((ext_vector_type(8)));
typedef float f32x4 __attribute__((ext_vector_type(4)));
typedef unsigned int u32;

#define CB 32
#define CF 128
#define CH 256
#define CT 2048
#define TCC 128    // chunk length (timesteps)
#define SEG 16
#define SLEN 128   // CT/SEG
#define SHBYTES 58368

static __device__ __forceinline__ f16x2 bc(u32 u){ return __builtin_bit_cast(f16x2, u); }
static __device__ __forceinline__ f16x8 bch8(uint4 u){ return __builtin_bit_cast(f16x8, u); }
static __device__ __forceinline__ u32 packh2(float lo, float hi){ f16x2 v; v.x=(f16)lo; v.y=(f16)hi; return __builtin_bit_cast(u32, v); }

static __device__ __forceinline__ float dot2f(f16x2 a, f16x2 b, float c){
#if defined(__has_builtin)
#if __has_builtin(__builtin_amdgcn_fdot2)
  return __builtin_amdgcn_fdot2(a, b, c, false);
#else
  return c + (float)a.x*(float)b.x + (float)a.y*(float)b.y;
#endif
#else
  return c + (float)a.x*(float)b.x + (float)a.y*(float)b.y;
#endif
}

// Pin a uint4 in VGPRs (tied 32-bit component operands; 128-bit "+v" is rejected).
#define PIN4(V) asm volatile("" : "+v"((V).x), "+v"((V).y), "+v"((V).z), "+v"((V).w))

// LDS-only barrier (no vmcnt drain): global loads are register-dep (compiler
// inserts its own vmcnt); global stores are consumed by the next launch.
#define RBAR() do { \
  asm volatile("s_waitcnt lgkmcnt(0)" ::: "memory"); \
  __builtin_amdgcn_s_barrier(); \
  asm volatile("" ::: "memory"); \
} while (0)

// ---------------- init ----------------
__global__ void init_hst(float* hst){
  int i = blockIdx.x*256 + threadIdx.x;
  if (i < 2*CB*CH) hst[i] = 0.f;
}

// ---------------- weight packing ----------------
static __device__ __forceinline__ float wc0src(int k, int n, const float* W0, const float* V0, const float* Wdh0){
  if (k < 128) return (n < 768) ? W0[k*768 + n] : 0.f;
  if (k < 256) return (n < 768) ? V0[(k-128)*768 + n] : 0.f;
  return (n >= 768) ? Wdh0[(k-256)*256 + (n-768)] : 0.f;
}
static __device__ __forceinline__ float wc1src(int k, int n, const float* W1, const float* V1, const float* Wdh1){
  if (k < 256) return (n < 768) ? W1[k*768 + n] : 0.f;
  if (k < 384) return (n < 768) ? V1[(k-256)*768 + n] : 0.f;
  return (n >= 768) ? Wdh1[(k-384)*256 + (n-768)] : 0.f;
}
// MFMA B-fragment packing (r19). Thread Lt (0..511) = wave wv (Lt>>6) lane l.
// Assumed (and self-consistent, see kernel comment) lane map for 16x16x32_f16:
//   A[row=l&15][k = kt*32 + (l>>4)*8 + i],  B[k same][col = l&15-based].
// rz frags: fi = nt*8+kt (nt<4): col = 64*wv + 16*nt + li (U cols 0..511 = r,z)
// c  frags: fi = nt*8+kt (nt<2): col = 512 + 32*wv + 16*nt + li
static __device__ __forceinline__ u32 wfrz_src(int j, const float* U){
  int fi = j >> 11, Lt = (j >> 2) & 511, d = j & 3;
  int wv = Lt >> 6, lg = (Lt >> 4) & 3, li = Lt & 15;
  int col = 64*wv + 16*(fi >> 3) + li;
  int k0 = (fi & 7)*32 + lg*8 + 2*d;
  return packh2(U[k0*768 + col], U[(k0+1)*768 + col]);
}
static __device__ __forceinline__ u32 wfc_src(int j, const float* U){
  int fi = j >> 11, Lt = (j >> 2) & 511, d = j & 3;
  int wv = Lt >> 6, lg = (Lt >> 4) & 3, li = Lt & 15;
  int col = 512 + 32*wv + 16*(fi >> 3) + li;
  int k0 = (fi & 7)*32 + lg*8 + 2*d;
  return packh2(U[k0*768 + col], U[(k0+1)*768 + col]);
}

__global__ __launch_bounds__(256) void pack_w(
    const float* __restrict__ W0, const float* __restrict__ V0, const float* __restrict__ Wdh0,
    const float* __restrict__ W1, const float* __restrict__ V1, const float* __restrict__ Wdh1,
    const float* __restrict__ U0, const float* __restrict__ U1,
    const float* __restrict__ b0, const float* __restrict__ bdh0,
    const float* __restrict__ b1, const float* __restrict__ bdh1,
    u32* __restrict__ WC0p, u32* __restrict__ WC1p,
    u32* __restrict__ WF0rz, u32* __restrict__ WF1rz,
    u32* __restrict__ WF0c, u32* __restrict__ WF1c,
    float* __restrict__ bias0, float* __restrict__ bias1){
  int idx = blockIdx.x*256 + threadIdx.x;
  if (idx < 196608){
    int k2 = idx >> 10, n = idx & 1023;
    WC0p[idx] = packh2(wc0src(2*k2, n, W0,V0,Wdh0), wc0src(2*k2+1, n, W0,V0,Wdh0));
  } else if (idx < 458752){
    int j = idx - 196608; int k2 = j >> 10, n = j & 1023;
    WC1p[j] = packh2(wc1src(2*k2, n, W1,V1,Wdh1), wc1src(2*k2+1, n, W1,V1,Wdh1));
  } else if (idx < 524288){
    WF0rz[idx - 458752] = wfrz_src(idx - 458752, U0);
  } else if (idx < 589824){
    WF1rz[idx - 524288] = wfrz_src(idx - 524288, U1);
  } else if (idx < 622592){
    WF0c[idx - 589824] = wfc_src(idx - 589824, U0);
  } else if (idx < 655360){
    WF1c[idx - 622592] = wfc_src(idx - 622592, U1);
  } else if (idx < 657408){
    int i = idx - 655360;
    if (i < 1024) bias0[i] = (i < 768) ? b0[i] : bdh0[i - 768];
    else { int j = i - 1024; bias1[j] = (j < 768) ? b1[j] : bdh1[j - 768]; }
  }
}

// ---------------- K1 (segmented, 16x parallel): forward-fill scan + fp16 pack ----------------
__global__ __launch_bounds__(256) void k1a(const float* __restrict__ in,
    float* __restrict__ segval, int* __restrict__ seghas){
  int tid = blockIdx.x*256 + threadIdx.x;      // 16 segs x 4096 chains
  int s = tid >> 12, chain = tid & 4095;
  int b = chain >> 7, f = chain & 127;
  const float* px = in + ((size_t)b*3 + 0)*CT*CF + f;
  const float* pm = in + ((size_t)b*3 + 1)*CT*CF + f;
  float last = 0.f; int has = 0;
  #pragma unroll 4
  for (int u = 0; u < SLEN; ++u){
    int t = s*SLEN + u;
    float m = pm[(size_t)t*CF], x = px[(size_t)t*CF];
    if (m > 0.f){ last = x; has = 1; }
  }
  segval[s*4096 + chain] = last;
  seghas[s*4096 + chain] = has;
}
__global__ __launch_bounds__(256) void k1b(const float* __restrict__ x_mean,
    const float* __restrict__ segval, const int* __restrict__ seghas, float* __restrict__ seed){
  int chain = blockIdx.x*256 + threadIdx.x;    // 4096 chains
  int f = chain & 127;
  float cur = x_mean[f];
  #pragma unroll
  for (int s = 0; s < SEG; ++s){
    seed[s*4096 + chain] = cur;
    if (seghas[s*4096 + chain]) cur = segval[s*4096 + chain];
  }
}
__global__ __launch_bounds__(256) void k1c(const float* __restrict__ in, const float* __restrict__ x_mean,
    const float* __restrict__ w_dx, const float* __restrict__ b_dx,
    const float* __restrict__ seed, f16* __restrict__ A){
  int tid = blockIdx.x*256 + threadIdx.x;
  int s = tid >> 12, chain = tid & 4095;
  int b = chain >> 7, f = chain & 127;
  const float wd = w_dx[f], bd = b_dx[f], xm = x_mean[f];
  const float* px = in + ((size_t)b*3 + 0)*CT*CF + f;
  const float* pm = in + ((size_t)b*3 + 1)*CT*CF + f;
  const float* pd = in + ((size_t)b*3 + 2)*CT*CF + f;
  float xl = seed[s*4096 + chain];
  #pragma unroll 4
  for (int u = 0; u < SLEN; ++u){
    int t = s*SLEN + u;
    float x = px[(size_t)t*CF], m = pm[(size_t)t*CF], d = pd[(size_t)t*CF];
    float gx = __expf(-fmaxf(d*wd + bd, 0.f));
    float xh = m*x + (1.f-m)*(gx*xl + (1.f-gx)*xm);
    f16* wq = A + ((size_t)t*CB + b)*384 + f;
    wq[0] = (f16)xh; wq[128] = (f16)m; wq[256] = (f16)d;
    xl = (m > 0.f) ? x : xl;
  }
}

// ---------------- GEMM tile (device fn, r4-proven): 64x64, 256 threads ----------------
static __device__ void gemm_tile(
    const u32* __restrict__ Aa, int lda, const u32* __restrict__ Ab, int ldb, int kasplit,
    int ktiles, const u32* __restrict__ Wp, const float* __restrict__ bias, float* __restrict__ Out,
    int row0, int n0, int tid, char* sm){
  u32 (*AsT)[68] = (u32 (*)[68])sm;
  u32 (*Bs)[64]  = (u32 (*)[64])(sm + 4352);
  const int tx = tid & 15, ty = tid >> 4;
  const int am = tid >> 2, akq = (tid & 3) * 4;
  const int bk = tid >> 4, bnq = (tid & 15) * 4;
  float acc[4][4] = {};
  for (int kt = 0; kt < ktiles; ++kt){
    int k2g = kt*16 + akq;
    uint4 ga;
    if (k2g < kasplit) ga = *(const uint4*)&Aa[(size_t)(row0 + am)*lda + k2g];
    else               ga = *(const uint4*)&Ab[(size_t)(row0 + am)*ldb + (k2g - kasplit)];
    uint4 gb = *(const uint4*)&Wp[(size_t)(kt*16 + bk)*1024 + n0 + bnq];
    __syncthreads();
    AsT[akq+0][am] = ga.x; AsT[akq+1][am] = ga.y; AsT[akq+2][am] = ga.z; AsT[akq+3][am] = ga.w;
    *(uint4*)&Bs[bk][bnq] = gb;
    __syncthreads();
    #pragma unroll
    for (int kk = 0; kk < 16; ++kk){
      uint4 bq = *(const uint4*)&Bs[kk][tx*4];
      uint4 aq = *(const uint4*)&AsT[kk][ty*4];
      f16x2 bv0 = bc(bq.x), bv1 = bc(bq.y), bv2 = bc(bq.z), bv3 = bc(bq.w);
      f16x2 av0 = bc(aq.x), av1 = bc(aq.y), av2 = bc(aq.z), av3 = bc(aq.w);
      acc[0][0] = dot2f(av0, bv0, acc[0][0]); acc[0][1] = dot2f(av0, bv1, acc[0][1]);
      acc[0][2] = dot2f(av0, bv2, acc[0][2]); acc[0][3] = dot2f(av0, bv3, acc[0][3]);
      acc[1][0] = dot2f(av1, bv0, acc[1][0]); acc[1][1] = dot2f(av1, bv1, acc[1][1]);
      acc[1][2] = dot2f(av1, bv2, acc[1][2]); acc[1][3] = dot2f(av1, bv3, acc[1][3]);
      acc[2][0] = dot2f(av2, bv0, acc[2][0]); acc[2][1] = dot2f(av2, bv1, acc[2][1]);
      acc[2][2] = dot2f(av2, bv2, acc[2][2]); acc[2][3] = dot2f(av2, bv3, acc[2][3]);
      acc[3][0] = dot2f(av3, bv0, acc[3][0]); acc[3][1] = dot2f(av3, bv1, acc[3][1]);
      acc[3][2] = dot2f(av3, bv2, acc[3][2]); acc[3][3] = dot2f(av3, bv3, acc[3][3]);
    }
  }
  const bool isg = (n0 >= 768);
  #pragma unroll
  for (int i = 0; i < 4; ++i){
    int r = row0 + ty*4 + i;
    int n = n0 + tx*4;
    float4 v;
    float* vv = (float*)&v;
    #pragma unroll
    for (int j = 0; j < 4; ++j){
      float x = acc[i][j] + bias[n + j];
      if (isg) x = __expf(-fmaxf(x, 0.f));
      vv[j] = x;
    }
    *(float4*)&Out[(size_t)r*1024 + n] = v;
  }
}

// ---------------- MEGA (r19): MFMA RNN. Blocks 0..3 = RNN (2 per layer, 16 rows each),
// blocks 4.. = GEMM. RNN per block: 8 waves; wave wv owns rz-cols [64wv,64wv+64) in
// phase 1 (wv<4 -> r, wv>=4 -> z) and c-cols [32wv,32wv+32) in phase 2.
// U in 192 pinned regs/thread as MFMA B-frags (MFMA reads them natively — no
// accvgpr-move tax, unlike r17's VALU dots). Any mis-assumption of the HW lane->k
// map cancels: A-read and B-pack use the SAME map, so the k-permutation is applied
// to both operands of the dot. Only the verified C/D map (row=(l>>4)*4+i, col=l&15)
// is load-bearing.
// LDS: h16[16][272] f16 (A), rh16 same, hdF/zF [256][20] f32 col-major (4-row b128).
__global__ __launch_bounds__(512, 2) void mega(
    const float* __restrict__ O0r, const float* __restrict__ O1r,
    const u32* __restrict__ WF0rz, const u32* __restrict__ WF1rz,
    const u32* __restrict__ WF0c, const u32* __restrict__ WF1c,
    float* __restrict__ hst, f16* __restrict__ h0cw, float* __restrict__ out,
    int t0_l1, int n0, int n1, int g0n, int g1n,
    const u32* __restrict__ g0a, float* __restrict__ g0out,
    const u32* __restrict__ g1a, const u32* __restrict__ g1b, float* __restrict__ g1out,
    const u32* __restrict__ WC0p, const u32* __restrict__ WC1p,
    const float* __restrict__ bias0, const float* __restrict__ bias1){
  extern __shared__ __align__(16) char smraw[];
  const int L = threadIdx.x;
  if (blockIdx.x >= 4){
    int gb = blockIdx.x - 4;
    int st = L >> 8, t2 = L & 255;
    char* smst = smraw + st*8448;
    if (gb < g0n){
      int tile = gb*2 + st;
      gemm_tile(g0a, 192, g0a, 192, 192, 12, WC0p, bias0, g0out, (tile>>4)*64, (tile&15)*64, t2, smst);
    } else {
      int tile = (gb - g0n)*2 + st;
      gemm_tile(g1a, 128, g1b, 192, 128, 16, WC1p, bias1, g1out, (tile>>4)*64, (tile&15)*64, t2, smst);
    }
    return;
  }
  // ---- RNN ----
  const int role = blockIdx.x >> 1;
  const int half = blockIdx.x & 1;
  const int steps = role ? n1 : n0;
  if (steps == 0) return;
  const float* O = role ? O1r : O0r;
  const u32* WFrz = role ? WF1rz : WF0rz;
  const u32* WFc  = role ? WF1c  : WF0c;
  const int r0g = half*16;
  float* hcarry = hst + role*CB*CH + r0g*CH;

  f16*  h16  = (f16*)smraw;                 // [16][272] f16, row-major (A-frags)
  f16*  rh16 = (f16*)(smraw + 8704);        // [16][272] f16
  float* hdF = (float*)(smraw + 17408);     // [256][20] f32 col-major
  float* zF  = (float*)(smraw + 37888);     // [256][20] f32 col-major

  const int l  = L & 63, wv = L >> 6;
  const int lg = l >> 4, li = l & 15;

  // weights -> 192 pinned regs
  uint4 wrz[32];
  #pragma unroll
  for (int i = 0; i < 32; ++i) wrz[i] = *(const uint4*)&WFrz[((size_t)i*512 + L)*4];
  uint4 wcf[16];
  #pragma unroll
  for (int i = 0; i < 16; ++i) wcf[i] = *(const uint4*)&WFc[((size_t)i*512 + L)*4];
  #pragma unroll
  for (int i = 0; i < 32; ++i) PIN4(wrz[i]);
  #pragma unroll
  for (int i = 0; i < 16; ++i) PIN4(wcf[i]);

  __builtin_amdgcn_s_setprio(1);

  // ---- init damped state: hd0 = gamma_0 * h_carry ----
  {
    int base = L*8;                       // 4096 = 16 rows x 256 j
    int row = base >> 8, j0 = base & 255;
    const float* gp = O + ((size_t)(r0g + row))*1024 + 768 + j0;
    float hd[8];
    #pragma unroll
    for (int e = 0; e < 8; ++e){
      hd[e] = gp[e] * hcarry[row*256 + j0 + e];
      hdF[(j0+e)*20 + row] = hd[e];
    }
    uint4 hw;
    hw.x = packh2(hd[0], hd[1]); hw.y = packh2(hd[2], hd[3]);
    hw.z = packh2(hd[4], hd[5]); hw.w = packh2(hd[6], hd[7]);
    *(uint4*)((char*)h16 + row*544 + j0*2) = hw;
  }
  // prefetch rz-pre for step 0
  float pre1[16];
  #pragma unroll
  for (int nt = 0; nt < 4; ++nt)
    #pragma unroll
    for (int i = 0; i < 4; ++i)
      pre1[nt*4+i] = O[((size_t)(r0g + 4*lg + i))*1024 + 64*wv + 16*nt + li];
  __syncthreads();

  for (int lt = 0; lt < steps; ++lt){
    const size_t rb = (size_t)(lt*32 + r0g);
    // ---- PHASE 1: rz ----
    f32x4 acc0 = {0.f,0.f,0.f,0.f}, acc1 = acc0, acc2 = acc0, acc3 = acc0;
    #pragma unroll
    for (int kt = 0; kt < 8; ++kt){
      f16x8 a = bch8(*(const uint4*)((const char*)h16 + li*544 + kt*64 + lg*16));
      acc0 = __builtin_amdgcn_mfma_f32_16x16x32_f16(a, bch8(wrz[kt]),      acc0, 0,0,0);
      acc1 = __builtin_amdgcn_mfma_f32_16x16x32_f16(a, bch8(wrz[8 + kt]),  acc1, 0,0,0);
      acc2 = __builtin_amdgcn_mfma_f32_16x16x32_f16(a, bch8(wrz[16 + kt]), acc2, 0,0,0);
      acc3 = __builtin_amdgcn_mfma_f32_16x16x32_f16(a, bch8(wrz[24 + kt]), acc3, 0,0,0);
    }
    if (wv < 4){
      #pragma unroll
      for (int nt = 0; nt < 4; ++nt){
        f32x4 ac = (nt==0)?acc0:(nt==1)?acc1:(nt==2)?acc2:acc3;
        int j1 = 64*wv + 16*nt + li;
        f32x4 hd4 = *(const f32x4*)&hdF[j1*20 + lg*4];
        #pragma unroll
        for (int i = 0; i < 4; ++i){
          float s1 = 1.f/(1.f + __expf(-(ac[i] + pre1[nt*4+i])));
          rh16[(4*lg+i)*272 + j1] = (f16)(s1 * hd4[i]);
        }
      }
    } else {
      #pragma unroll
      for (int nt = 0; nt < 4; ++nt){
        f32x4 ac = (nt==0)?acc0:(nt==1)?acc1:(nt==2)?acc2:acc3;
        int jz = 64*(wv-4) + 16*nt + li;
        f32x4 zv;
        #pragma unroll
        for (int i = 0; i < 4; ++i) zv[i] = 1.f/(1.f + __expf(-(ac[i] + pre1[nt*4+i])));
        *(f32x4*)&zF[jz*20 + lg*4] = zv;
      }
    }
    RBAR(); // B1: rh16, zF ready
    // ---- PHASE 2: c ----
    const int ltn = (lt+1 < steps) ? lt+1 : lt;
    float pc[8], gmn[8];
    #pragma unroll
    for (int nt = 0; nt < 2; ++nt)
      #pragma unroll
      for (int i = 0; i < 4; ++i){
        int j2 = 32*wv + 16*nt + li;
        pc[nt*4+i]  = O[(rb + 4*lg + i)*1024 + 512 + j2];
        gmn[nt*4+i] = O[((size_t)(ltn*32 + r0g) + 4*lg + i)*1024 + 768 + j2];
      }
    f32x4 acc4 = {0.f,0.f,0.f,0.f}, acc5 = acc4;
    #pragma unroll
    for (int kt = 0; kt < 8; ++kt){
      f16x8 a = bch8(*(const uint4*)((const char*)rh16 + li*544 + kt*64 + lg*16));
      acc4 = __builtin_amdgcn_mfma_f32_16x16x32_f16(a, bch8(wcf[kt]),     acc4, 0,0,0);
      acc5 = __builtin_amdgcn_mfma_f32_16x16x32_f16(a, bch8(wcf[8 + kt]), acc5, 0,0,0);
    }
    #pragma unroll
    for (int nt = 0; nt < 2; ++nt){
      f32x4 ac = (nt==0)?acc4:acc5;
      int j2 = 32*wv + 16*nt + li;
      f32x4 zv  = *(const f32x4*)&zF[j2*20 + lg*4];
      f32x4 hd4 = *(const f32x4*)&hdF[j2*20 + lg*4];
      f32x4 hdn4;
      #pragma unroll
      for (int i = 0; i < 4; ++i){
        float v = ac[i] + pc[nt*4+i];
        float e = __expf(2.f*v);
        float ct = 1.f - 2.f/(1.f + e);
        float hn = hd4[i] + zv[i]*(ct - hd4[i]);
        if (role == 0) h0cw[(rb + 4*lg + i)*256 + j2] = (f16)hn;
        else           out[((size_t)((t0_l1 + lt)*32 + r0g) + 4*lg + i)*256 + j2] = hn;
        if (lt == steps-1) hcarry[(4*lg+i)*256 + j2] = hn;
        float hdn = gmn[nt*4+i]*hn;
        hdn4[i] = hdn;
        h16[(4*lg+i)*272 + j2] = (f16)hdn;
      }
      *(f32x4*)&hdF[j2*20 + lg*4] = hdn4;
    }
    // prefetch next rz-pre
    if (lt+1 < steps){
      #pragma unroll
      for (int nt = 0; nt < 4; ++nt)
        #pragma unroll
        for (int i = 0; i < 4; ++i)
          pre1[nt*4+i] = O[((size_t)((lt+1)*32 + r0g) + 4*lg + i)*1024 + 64*wv + 16*nt + li];
    }
    RBAR(); // C: h16/hdF ready for next step
  }
}

// ---------------- host ----------------
extern "C" void kernel_launch(void* const* d_in, const int* in_sizes, int n_in,
                              void* d_out, int out_size, void* d_ws, size_t ws_size,
                              hipStream_t stream){
  const float* input  = (const float*)d_in[0];
  const float* x_mean = (const float*)d_in[1];
  const float* w_dx   = (const float*)d_in[2];
  const float* b_dx   = (const float*)d_in[3];
  const float* Wdh0   = (const float*)d_in[4];
  const float* bdh0   = (const float*)d_in[5];
  const float* W0     = (const float*)d_in[6];
  const float* U0     = (const float*)d_in[7];
  const float* V0     = (const float*)d_in[8];
  const float* b0     = (const float*)d_in[9];
  const float* Wdh1   = (const float*)d_in[10];
  const float* bdh1   = (const float*)d_in[11];
  const float* W1     = (const float*)d_in[12];
  const float* U1     = (const float*)d_in[13];
  const float* V1     = (const float*)d_in[14];
  const float* b1     = (const float*)d_in[15];
  float* out = (float*)d_out;

  hipFuncSetAttribute((const void*)mega, hipFuncAttributeMaxDynamicSharedMemorySize, SHBYTES);

  char* base = (char*)d_ws;
  size_t off = 0;
  auto take = [&](size_t bytes)->char*{
    char* p = base + off;
    off = (off + bytes + 255) & ~(size_t)255;
    return p;
  };
  f16*  IN0h  = (f16*) take((size_t)CT*CB*384*2);     // 48 MB
  u32*  WC0p  = (u32*) take((size_t)192*1024*4);
  u32*  WC1p  = (u32*) take((size_t)256*1024*4);
  u32*  WF0rz = (u32*) take((size_t)32*512*4*4);      // 256 KB
  u32*  WF1rz = (u32*) take((size_t)32*512*4*4);
  u32*  WF0c  = (u32*) take((size_t)16*512*4*4);      // 128 KB
  u32*  WF1c  = (u32*) take((size_t)16*512*4*4);
  float* bias0= (float*)take(1024*4);
  float* bias1= (float*)take(1024*4);
  float* hst  = (float*)take((size_t)2*CB*CH*4);
  float* segv = (float*)take((size_t)SEG*4096*4);
  int*   segh = (int*)  take((size_t)SEG*4096*4);
  float* seed = (float*)take((size_t)SEG*4096*4);
  float* O0b[2], *O1b[2]; f16* h0b[2];
  O0b[0] = (float*)take((size_t)TCC*CB*1024*4);       // 16.8 MB each
  O0b[1] = (float*)take((size_t)TCC*CB*1024*4);
  O1b[0] = (float*)take((size_t)TCC*CB*1024*4);
  O1b[1] = (float*)take((size_t)TCC*CB*1024*4);
  h0b[0] = (f16*)  take((size_t)TCC*CB*CH*2);
  h0b[1] = (f16*)  take((size_t)TCC*CB*CH*2);

  hipLaunchKernelGGL(init_hst, dim3(64), dim3(256), 0, stream, hst);
  hipLaunchKernelGGL(pack_w, dim3((657408 + 255)/256), dim3(256), 0, stream,
      W0, V0, Wdh0, W1, V1, Wdh1, U0, U1, b0, bdh0, b1, bdh1,
      WC0p, WC1p, WF0rz, WF1rz, WF0c, WF1c, bias0, bias1);
  hipLaunchKernelGGL(k1a, dim3(256), dim3(256), 0, stream, input, segv, segh);
  hipLaunchKernelGGL(k1b, dim3(16), dim3(256), 0, stream, x_mean, segv, segh, seed);
  hipLaunchKernelGGL(k1c, dim3(256), dim3(256), 0, stream, input, x_mean, w_dx, b_dx, seed, IN0h);

  const u32* IN0p = (const u32*)IN0h;
  const int nch = CT / TCC;   // 16
  for (int i = -1; i <= nch + 1; ++i){
    int r0 = (i >= 0 && i < nch) ? 1 : 0;
    int r1 = (i >= 2 && i < nch + 2) ? 1 : 0;
    int g0 = (i + 1 >= 0 && i + 1 < nch) ? 1 : 0;
    int g1 = (i - 1 >= 0 && i - 1 < nch) ? 1 : 0;
    int g0n = g0 ? 512 : 0, g1n = g1 ? 512 : 0;
    const float* O0r = O0b[i & 1];
    const float* O1r = O1b[i & 1];
    f16* h0cw = h0b[i & 1];
    const u32* g0a = IN0p + (size_t)(i+1)*TCC*CB*192;
    float* g0out = O0b[(i+1) & 1];
    const u32* g1a = (const u32*)h0b[(i-1) & 1];
    const u32* g1b = IN0p + (size_t)(i-1)*TCC*CB*192 + 64;
    float* g1out = O1b[(i-1) & 1];
    hipLaunchKernelGGL(mega, dim3(4 + g0n + g1n), dim3(512), SHBYTES, stream,
        O0r, O1r, WF0rz, WF1rz, WF0c, WF1c, hst, h0cw, out,
        (i-2)*TCC, r0 ? TCC : 0, r1 ? TCC : 0, g0n, g1n,
        g0a, g0out, g1a, g1b, g1out,
        WC0p, WC1p, bias0, bias1);
  }
}

// Round 7
// 3154.276 us; speedup vs baseline: 3.1831x; 3.1831x over previous
//
#include <hip/hip_runtime.h>

typedef _Float16 f16;
typedef _Float16 f16x2 __attribute__((ext_vector_type(2)));
typedef unsigned int u32;

#define CB 32
#define CF 128
#define CH 256
#define CT 2048
#define TCC 64     // chunk length (timesteps). r20: 128->64 halves the 2-chunk pipeline
                   // lag (256->128 wasted step-slots) at ~+16 launches of overhead.
#define SEG 16
#define SLEN 128   // CT/SEG
#define SHBYTES 16896
#define GBLK ((TCC*CB/64)*16/2)   // GEMM blocks per producer (2 tiles each) = 256 at TCC=64

static __device__ __forceinline__ f16x2 bc(u32 u){ return __builtin_bit_cast(f16x2, u); }
static __device__ __forceinline__ u32 packh2(float lo, float hi){ f16x2 v; v.x=(f16)lo; v.y=(f16)hi; return __builtin_bit_cast(u32, v); }

static __device__ __forceinline__ float dot2f(f16x2 a, f16x2 b, float c){
#if defined(__has_builtin)
#if __has_builtin(__builtin_amdgcn_fdot2)
  return __builtin_amdgcn_fdot2(a, b, c, false);
#else
  return c + (float)a.x*(float)b.x + (float)a.y*(float)b.y;
#endif
#else
  return c + (float)a.x*(float)b.x + (float)a.y*(float)b.y;
#endif
}
static __device__ __forceinline__ float dot4q(float acc, uint4 w, uint4 h){
  acc = dot2f(bc(w.x), bc(h.x), acc);
  acc = dot2f(bc(w.y), bc(h.y), acc);
  acc = dot2f(bc(w.z), bc(h.z), acc);
  acc = dot2f(bc(w.w), bc(h.w), acc);
  return acc;
}

// DPP butterfly add: x += lane-swapped x, swap within quads (xor 1 -> quad_perm
// [1,0,3,2] = 0xB1; xor 2 -> [2,3,0,1] = 0x4E). VALU-pipe (~10cy) instead of the
// ds_bpermute (~100+cy LDS-pipe) that __shfl_xor lowers to. Bit-identical sums.
template<int CTRL>
static __device__ __forceinline__ float dppx(float x){
  int v = __builtin_amdgcn_update_dpp(0, __builtin_bit_cast(int, x), CTRL, 0xF, 0xF, true);
  return x + __builtin_bit_cast(float, v);
}

// Pin a uint4 in VGPRs (tied 32-bit component operands; 128-bit "+v" is rejected).
#define PIN4(V) asm volatile("" : "+v"((V).x), "+v"((V).y), "+v"((V).z), "+v"((V).w))

// LDS-only barrier (no vmcnt drain): global loads are register-dep (compiler
// inserts its own vmcnt); global stores are consumed by the next launch.
#define RBAR() do { \
  asm volatile("s_waitcnt lgkmcnt(0)" ::: "memory"); \
  __builtin_amdgcn_s_barrier(); \
  asm volatile("" ::: "memory"); \
} while (0)

// ---------------- init ----------------
__global__ void init_hst(float* hst){
  int i = blockIdx.x*256 + threadIdx.x;
  if (i < 2*CB*CH) hst[i] = 0.f;
}

// ---------------- weight packing ----------------
static __device__ __forceinline__ float wc0src(int k, int n, const float* W0, const float* V0, const float* Wdh0){
  if (k < 128) return (n < 768) ? W0[k*768 + n] : 0.f;
  if (k < 256) return (n < 768) ? V0[(k-128)*768 + n] : 0.f;
  return (n >= 768) ? Wdh0[(k-256)*256 + (n-768)] : 0.f;
}
static __device__ __forceinline__ float wc1src(int k, int n, const float* W1, const float* V1, const float* Wdh1){
  if (k < 256) return (n < 768) ? W1[k*768 + n] : 0.f;
  if (k < 384) return (n < 768) ? V1[(k-256)*768 + n] : 0.f;
  return (n >= 768) ? Wdh1[(k-384)*256 + (n-768)] : 0.f;
}
// K3 recurrent weights, 512-thread 4-way-K-split. Thread L: p=L>>2, q=L&3.
// rz flats (cc*8+j, 32 total), c flats (cc2*8+j, 16 total).
static __device__ __forceinline__ u32 wrz_pair(int flat, int jj, int L, const float* U){
  int p = L >> 2, q = L & 3;
  int cc = flat >> 3, j = flat & 7;
  int col = 4*p + cc;
  int pr = 32*q + 4*j + jj;
  return packh2(U[(2*pr)*768 + col], U[(2*pr+1)*768 + col]);
}
static __device__ __forceinline__ u32 wcc_pair(int flat, int jj, int L, const float* U){
  int p = L >> 2, q = L & 3;
  int cc2 = flat >> 3, j = flat & 7;
  int col = 512 + 2*p + cc2;
  int pr = 32*q + 4*j + jj;
  return packh2(U[(2*pr)*768 + col], U[(2*pr+1)*768 + col]);
}

__global__ __launch_bounds__(256) void pack_w(
    const float* __restrict__ W0, const float* __restrict__ V0, const float* __restrict__ Wdh0,
    const float* __restrict__ W1, const float* __restrict__ V1, const float* __restrict__ Wdh1,
    const float* __restrict__ U0, const float* __restrict__ U1,
    const float* __restrict__ b0, const float* __restrict__ bdh0,
    const float* __restrict__ b1, const float* __restrict__ bdh1,
    u32* __restrict__ WC0p, u32* __restrict__ WC1p,
    u32* __restrict__ WRZa, u32* __restrict__ WRZb,
    u32* __restrict__ WCCa, u32* __restrict__ WCCb,
    float* __restrict__ bias0, float* __restrict__ bias1){
  int idx = blockIdx.x*256 + threadIdx.x;
  if (idx < 196608){
    int k2 = idx >> 10, n = idx & 1023;
    WC0p[idx] = packh2(wc0src(2*k2, n, W0,V0,Wdh0), wc0src(2*k2+1, n, W0,V0,Wdh0));
  } else if (idx < 458752){
    int j = idx - 196608; int k2 = j >> 10, n = j & 1023;
    WC1p[j] = packh2(wc1src(2*k2, n, W1,V1,Wdh1), wc1src(2*k2+1, n, W1,V1,Wdh1));
  } else if (idx < 524288){
    int j = idx - 458752; int flat = j >> 11, L = (j >> 2) & 511, jj = j & 3;
    WRZa[j] = wrz_pair(flat, jj, L, U0);
  } else if (idx < 589824){
    int j = idx - 524288; int flat = j >> 11, L = (j >> 2) & 511, jj = j & 3;
    WRZb[j] = wrz_pair(flat, jj, L, U1);
  } else if (idx < 622592){
    int j = idx - 589824; int flat = j >> 11, L = (j >> 2) & 511, jj = j & 3;
    WCCa[j] = wcc_pair(flat, jj, L, U0);
  } else if (idx < 655360){
    int j = idx - 622592; int flat = j >> 11, L = (j >> 2) & 511, jj = j & 3;
    WCCb[j] = wcc_pair(flat, jj, L, U1);
  } else if (idx < 657408){
    int i = idx - 655360;
    if (i < 1024) bias0[i] = (i < 768) ? b0[i] : bdh0[i - 768];
    else { int j = i - 1024; bias1[j] = (j < 768) ? b1[j] : bdh1[j - 768]; }
  }
}

// ---------------- K1 (segmented, 16x parallel): forward-fill scan + fp16 pack ----------------
__global__ __launch_bounds__(256) void k1a(const float* __restrict__ in,
    float* __restrict__ segval, int* __restrict__ seghas){
  int tid = blockIdx.x*256 + threadIdx.x;      // 16 segs x 4096 chains
  int s = tid >> 12, chain = tid & 4095;
  int b = chain >> 7, f = chain & 127;
  const float* px = in + ((size_t)b*3 + 0)*CT*CF + f;
  const float* pm = in + ((size_t)b*3 + 1)*CT*CF + f;
  float last = 0.f; int has = 0;
  #pragma unroll 4
  for (int u = 0; u < SLEN; ++u){
    int t = s*SLEN + u;
    float m = pm[(size_t)t*CF], x = px[(size_t)t*CF];
    if (m > 0.f){ last = x; has = 1; }
  }
  segval[s*4096 + chain] = last;
  seghas[s*4096 + chain] = has;
}
__global__ __launch_bounds__(256) void k1b(const float* __restrict__ x_mean,
    const float* __restrict__ segval, const int* __restrict__ seghas, float* __restrict__ seed){
  int chain = blockIdx.x*256 + threadIdx.x;    // 4096 chains
  int f = chain & 127;
  float cur = x_mean[f];
  #pragma unroll
  for (int s = 0; s < SEG; ++s){
    seed[s*4096 + chain] = cur;
    if (seghas[s*4096 + chain]) cur = segval[s*4096 + chain];
  }
}
__global__ __launch_bounds__(256) void k1c(const float* __restrict__ in, const float* __restrict__ x_mean,
    const float* __restrict__ w_dx, const float* __restrict__ b_dx,
    const float* __restrict__ seed, f16* __restrict__ A){
  int tid = blockIdx.x*256 + threadIdx.x;
  int s = tid >> 12, chain = tid & 4095;
  int b = chain >> 7, f = chain & 127;
  const float wd = w_dx[f], bd = b_dx[f], xm = x_mean[f];
  const float* px = in + ((size_t)b*3 + 0)*CT*CF + f;
  const float* pm = in + ((size_t)b*3 + 1)*CT*CF + f;
  const float* pd = in + ((size_t)b*3 + 2)*CT*CF + f;
  float xl = seed[s*4096 + chain];
  #pragma unroll 4
  for (int u = 0; u < SLEN; ++u){
    int t = s*SLEN + u;
    float x = px[(size_t)t*CF], m = pm[(size_t)t*CF], d = pd[(size_t)t*CF];
    float gx = __expf(-fmaxf(d*wd + bd, 0.f));
    float xh = m*x + (1.f-m)*(gx*xl + (1.f-gx)*xm);
    f16* wq = A + ((size_t)t*CB + b)*384 + f;
    wq[0] = (f16)xh; wq[128] = (f16)m; wq[256] = (f16)d;
    xl = (m > 0.f) ? x : xl;
  }
}

// ---------------- GEMM tile (device fn, r4-proven): 64x64, 256 threads ----------------
static __device__ void gemm_tile(
    const u32* __restrict__ Aa, int lda, const u32* __restrict__ Ab, int ldb, int kasplit,
    int ktiles, const u32* __restrict__ Wp, const float* __restrict__ bias, float* __restrict__ Out,
    int row0, int n0, int tid, char* sm){
  u32 (*AsT)[68] = (u32 (*)[68])sm;
  u32 (*Bs)[64]  = (u32 (*)[64])(sm + 4352);
  const int tx = tid & 15, ty = tid >> 4;
  const int am = tid >> 2, akq = (tid & 3) * 4;
  const int bk = tid >> 4, bnq = (tid & 15) * 4;
  float acc[4][4] = {};
  for (int kt = 0; kt < ktiles; ++kt){
    int k2g = kt*16 + akq;
    uint4 ga;
    if (k2g < kasplit) ga = *(const uint4*)&Aa[(size_t)(row0 + am)*lda + k2g];
    else               ga = *(const uint4*)&Ab[(size_t)(row0 + am)*ldb + (k2g - kasplit)];
    uint4 gb = *(const uint4*)&Wp[(size_t)(kt*16 + bk)*1024 + n0 + bnq];
    __syncthreads();
    AsT[akq+0][am] = ga.x; AsT[akq+1][am] = ga.y; AsT[akq+2][am] = ga.z; AsT[akq+3][am] = ga.w;
    *(uint4*)&Bs[bk][bnq] = gb;
    __syncthreads();
    #pragma unroll
    for (int kk = 0; kk < 16; ++kk){
      uint4 bq = *(const uint4*)&Bs[kk][tx*4];
      uint4 aq = *(const uint4*)&AsT[kk][ty*4];
      f16x2 bv0 = bc(bq.x), bv1 = bc(bq.y), bv2 = bc(bq.z), bv3 = bc(bq.w);
      f16x2 av0 = bc(aq.x), av1 = bc(aq.y), av2 = bc(aq.z), av3 = bc(aq.w);
      acc[0][0] = dot2f(av0, bv0, acc[0][0]); acc[0][1] = dot2f(av0, bv1, acc[0][1]);
      acc[0][2] = dot2f(av0, bv2, acc[0][2]); acc[0][3] = dot2f(av0, bv3, acc[0][3]);
      acc[1][0] = dot2f(av1, bv0, acc[1][0]); acc[1][1] = dot2f(av1, bv1, acc[1][1]);
      acc[1][2] = dot2f(av1, bv2, acc[1][2]); acc[1][3] = dot2f(av1, bv3, acc[1][3]);
      acc[2][0] = dot2f(av2, bv0, acc[2][0]); acc[2][1] = dot2f(av2, bv1, acc[2][1]);
      acc[2][2] = dot2f(av2, bv2, acc[2][2]); acc[2][3] = dot2f(av2, bv3, acc[2][3]);
      acc[3][0] = dot2f(av3, bv0, acc[3][0]); acc[3][1] = dot2f(av3, bv1, acc[3][1]);
      acc[3][2] = dot2f(av3, bv2, acc[3][2]); acc[3][3] = dot2f(av3, bv3, acc[3][3]);
    }
  }
  const bool isg = (n0 >= 768);
  #pragma unroll
  for (int i = 0; i < 4; ++i){
    int r = row0 + ty*4 + i;
    int n = n0 + tx*4;
    float4 v;
    float* vv = (float*)&v;
    #pragma unroll
    for (int j = 0; j < 4; ++j){
      float x = acc[i][j] + bias[n + j];
      if (isg) x = __expf(-fmaxf(x, 0.f));
      vv[j] = x;
    }
    *(float4*)&Out[(size_t)r*1024 + n] = v;
  }
}

// ---------------- MEGA: rnn (blocks 0..63, 1 row each) + gemm (blocks 64..), 512 threads ----------------
// r20 = r18 verbatim (verified 192us/launch at TCC=128), relaunched at TCC=64.
// r19's MFMA rewrite scratch-spilled (live set ~270 > 256 regs: 192 pinned weights
// + 24 acc + 32 prefetch + addressing) -> 3x/step regression; reverted.
__global__ __launch_bounds__(512, 2) void mega(
    const float* __restrict__ O0r, const float* __restrict__ O1r,
    const u32* __restrict__ WRZa, const u32* __restrict__ WRZb,
    const u32* __restrict__ WCCa, const u32* __restrict__ WCCb,
    float* __restrict__ hst, f16* __restrict__ h0cw, float* __restrict__ out,
    int t0_l1, int n0, int n1, int g0n, int g1n,
    const u32* __restrict__ g0a, float* __restrict__ g0out,
    const u32* __restrict__ g1a, const u32* __restrict__ g1b, float* __restrict__ g1out,
    const u32* __restrict__ WC0p, const u32* __restrict__ WC1p,
    const float* __restrict__ bias0, const float* __restrict__ bias1){
  extern __shared__ __align__(16) char smraw[];
  const int L = threadIdx.x;
  if (blockIdx.x >= 64){
    int gb = blockIdx.x - 64;
    int st = L >> 8, t2 = L & 255;
    char* smst = smraw + st*8448;
    if (gb < g0n){
      int tile = gb*2 + st;
      gemm_tile(g0a, 192, g0a, 192, 192, 12, WC0p, bias0, g0out, (tile>>4)*64, (tile&15)*64, t2, smst);
    } else {
      int tile = (gb - g0n)*2 + st;
      gemm_tile(g1a, 128, g1b, 192, 128, 16, WC1p, bias1, g1out, (tile>>4)*64, (tile&15)*64, t2, smst);
    }
    return;
  }
  // ---- RNN ----
  const int role = blockIdx.x >> 5;
  const int b = blockIdx.x & 31;
  const int steps = role ? n1 : n0;
  if (steps == 0) return;
  const float* O = role ? O1r : O0r;
  const u32* WRZ = role ? WRZb : WRZa;
  const u32* WCC = role ? WCCb : WCCa;
  float* hcarry = hst + role*CB*CH;

  f16*  hdh_  = (f16*)(smraw);            // 4 quarters x 80 f16 (160B stride), 640 B
  f16*  rh_   = (f16*)(smraw + 640);      // 4 quarters x 80 f16, 640 B
  float* hdf  = (float*)(smraw + 1280);   // 256 f32
  float* zz   = (float*)(smraw + 2304);   // 256 f32

  // All 48 recurrent-weight quads -> registers (192 words; unified VGPR/AGPR file),
  // then PIN (see PIN4).
  uint4 wrz[32];
  #pragma unroll
  for (int i = 0; i < 32; ++i) wrz[i] = *(const uint4*)&WRZ[((size_t)i*512 + L)*4];
  uint4 wcc[16];
  #pragma unroll
  for (int i = 0; i < 16; ++i) wcc[i] = *(const uint4*)&WCC[((size_t)i*512 + L)*4];
  #pragma unroll
  for (int i = 0; i < 32; ++i) PIN4(wrz[i]);
  #pragma unroll
  for (int i = 0; i < 16; ++i) PIN4(wcc[i]);

  __builtin_amdgcn_s_setprio(1);   // RNN waves are the sequential critical path

  const int p = L >> 2, q = L & 3;
  size_t row = (size_t)b*1024;
  if (L < 256){
    float hd = O[row + 768 + L] * hcarry[b*256 + L];
    hdf[L] = hd; hdh_[(L>>6)*80 + (L&63)] = (f16)hd;
  }
  float prz = O[row + L];
  const int e2 = 2*p + (q & 1);
  float pc = (q < 2) ? O[row + 512 + e2] : 0.f;
  const char* hqb = (const char*)hdh_ + q*160;
  const char* rqb = (const char*)rh_ + q*160;
  __syncthreads();

  for (int lt = 0; lt < steps; ++lt){
    size_t nrow = row + (size_t)CB*1024;
    float nprz = 0.f, npc = 0.f, ngex = 0.f;
    if (lt + 1 < steps){
      nprz = O[nrow + L];
      if (q < 2){ npc = O[nrow + 512 + e2]; ngex = O[nrow + 768 + e2]; }
    }
    // Preload this step's hdf values (ready since barrier C of previous step):
    float hdL = (L < 256) ? hdf[L] : 0.f;   // for rh_ write at end of phase 1
    float hd2 = hdf[e2];                    // for the h-update at end of phase 2
    // ---- PHASE 1: rz, 4 cols x quarter-K (skewed quarter reads, conflict-free) ----
    float a0=0.f, a1=0.f, a2=0.f, a3=0.f;
    #pragma unroll
    for (int j = 0; j < 8; ++j){
      uint4 h = ((const uint4*)hqb)[j];
      a0 = dot4q(a0, wrz[j],      h);
      a1 = dot4q(a1, wrz[8 + j],  h);
      a2 = dot4q(a2, wrz[16 + j], h);
      a3 = dot4q(a3, wrz[24 + j], h);
    }
    a0 = dppx<0xB1>(a0); a1 = dppx<0xB1>(a1); a2 = dppx<0xB1>(a2); a3 = dppx<0xB1>(a3);
    a0 = dppx<0x4E>(a0); a1 = dppx<0x4E>(a1); a2 = dppx<0x4E>(a2); a3 = dppx<0x4E>(a3);
    float sum1 = (q == 0) ? a0 : (q == 1) ? a1 : (q == 2) ? a2 : a3;   // col L total
    float s1 = 1.f/(1.f + __expf(-(sum1 + prz)));
    if (L < 256) rh_[(L>>6)*80 + (L&63)] = (f16)(s1 * hdL);
    else zz[L - 256] = s1;
    RBAR(); // B1: rh, zz ready (LDS-only barrier)
    float z = zz[e2];                       // hide LDS latency under c-dots
    // ---- PHASE 2: c, 2 cols x quarter-K ----
    float b0_=0.f, b1_=0.f;
    #pragma unroll
    for (int j = 0; j < 8; ++j){
      uint4 r = ((const uint4*)rqb)[j];
      b0_ = dot4q(b0_, wcc[j],     r);
      b1_ = dot4q(b1_, wcc[8 + j], r);
    }
    b0_ = dppx<0xB1>(b0_); b1_ = dppx<0xB1>(b1_);
    b0_ = dppx<0x4E>(b0_); b1_ = dppx<0x4E>(b1_);
    if (q < 2){
      float sumc = (q & 1) ? b1_ : b0_;
      float v = pc + sumc;
      float e = __expf(2.f*v);
      float ct = 1.f - 2.f/(1.f + e);   // tanh(v)
      float hd = hd2;
      float hn = hd + z*(ct - hd);
      float hdn = ngex*hn;
      hdf[e2] = hdn; hdh_[(e2>>6)*80 + (e2&63)] = (f16)hdn;
      if (role == 0) h0cw[((size_t)lt*CB + b)*256 + e2] = (f16)hn;
      else           out[((size_t)(t0_l1 + lt)*CB + b)*256 + e2] = hn;
      if (lt == steps-1) hcarry[b*256 + e2] = hn;
    }
    prz = nprz; pc = npc;
    row = nrow;
    RBAR(); // C: hdh/hdf ready for next step; rh/zz free (LDS-only barrier)
  }
}

// ---------------- host ----------------
extern "C" void kernel_launch(void* const* d_in, const int* in_sizes, int n_in,
                              void* d_out, int out_size, void* d_ws, size_t ws_size,
                              hipStream_t stream){
  const float* input  = (const float*)d_in[0];
  const float* x_mean = (const float*)d_in[1];
  const float* w_dx   = (const float*)d_in[2];
  const float* b_dx   = (const float*)d_in[3];
  const float* Wdh0   = (const float*)d_in[4];
  const float* bdh0   = (const float*)d_in[5];
  const float* W0     = (const float*)d_in[6];
  const float* U0     = (const float*)d_in[7];
  const float* V0     = (const float*)d_in[8];
  const float* b0     = (const float*)d_in[9];
  const float* Wdh1   = (const float*)d_in[10];
  const float* bdh1   = (const float*)d_in[11];
  const float* W1     = (const float*)d_in[12];
  const float* U1     = (const float*)d_in[13];
  const float* V1     = (const float*)d_in[14];
  const float* b1     = (const float*)d_in[15];
  float* out = (float*)d_out;

  hipFuncSetAttribute((const void*)mega, hipFuncAttributeMaxDynamicSharedMemorySize, SHBYTES);

  char* base = (char*)d_ws;
  size_t off = 0;
  auto take = [&](size_t bytes)->char*{
    char* p = base + off;
    off = (off + bytes + 255) & ~(size_t)255;
    return p;
  };
  f16*  IN0h  = (f16*) take((size_t)CT*CB*384*2);     // 48 MB
  u32*  WC0p  = (u32*) take((size_t)192*1024*4);
  u32*  WC1p  = (u32*) take((size_t)256*1024*4);
  u32*  WRZa  = (u32*) take((size_t)32*512*4*4);      // 256 KB
  u32*  WRZb  = (u32*) take((size_t)32*512*4*4);
  u32*  WCCa  = (u32*) take((size_t)16*512*4*4);      // 128 KB
  u32*  WCCb  = (u32*) take((size_t)16*512*4*4);
  float* bias0= (float*)take(1024*4);
  float* bias1= (float*)take(1024*4);
  float* hst  = (float*)take((size_t)2*CB*CH*4);
  float* segv = (float*)take((size_t)SEG*4096*4);
  int*   segh = (int*)  take((size_t)SEG*4096*4);
  float* seed = (float*)take((size_t)SEG*4096*4);
  float* O0b[2], *O1b[2]; f16* h0b[2];
  O0b[0] = (float*)take((size_t)TCC*CB*1024*4);       // 8.4 MB each at TCC=64
  O0b[1] = (float*)take((size_t)TCC*CB*1024*4);
  O1b[0] = (float*)take((size_t)TCC*CB*1024*4);
  O1b[1] = (float*)take((size_t)TCC*CB*1024*4);
  h0b[0] = (f16*)  take((size_t)TCC*CB*CH*2);
  h0b[1] = (f16*)  take((size_t)TCC*CB*CH*2);

  hipLaunchKernelGGL(init_hst, dim3(64), dim3(256), 0, stream, hst);
  hipLaunchKernelGGL(pack_w, dim3((657408 + 255)/256), dim3(256), 0, stream,
      W0, V0, Wdh0, W1, V1, Wdh1, U0, U1, b0, bdh0, b1, bdh1,
      WC0p, WC1p, WRZa, WRZb, WCCa, WCCb, bias0, bias1);
  hipLaunchKernelGGL(k1a, dim3(256), dim3(256), 0, stream, input, segv, segh);
  hipLaunchKernelGGL(k1b, dim3(16), dim3(256), 0, stream, x_mean, segv, segh, seed);
  hipLaunchKernelGGL(k1c, dim3(256), dim3(256), 0, stream, input, x_mean, w_dx, b_dx, seed, IN0h);

  const u32* IN0p = (const u32*)IN0h;
  const int nch = CT / TCC;   // 32 at TCC=64
  for (int i = -1; i <= nch + 1; ++i){
    int r0 = (i >= 0 && i < nch) ? 1 : 0;
    int r1 = (i >= 2 && i < nch + 2) ? 1 : 0;
    int g0 = (i + 1 >= 0 && i + 1 < nch) ? 1 : 0;
    int g1 = (i - 1 >= 0 && i - 1 < nch) ? 1 : 0;
    int g0n = g0 ? GBLK : 0, g1n = g1 ? GBLK : 0;
    const float* O0r = O0b[i & 1];
    const float* O1r = O1b[i & 1];
    f16* h0cw = h0b[i & 1];
    const u32* g0a = IN0p + (size_t)(i+1)*TCC*CB*192;
    float* g0out = O0b[(i+1) & 1];
    const u32* g1a = (const u32*)h0b[(i-1) & 1];
    const u32* g1b = IN0p + (size_t)(i-1)*TCC*CB*192 + 64;
    float* g1out = O1b[(i-1) & 1];
    hipLaunchKernelGGL(mega, dim3(64 + g0n + g1n), dim3(512), SHBYTES, stream,
        O0r, O1r, WRZa, WRZb, WCCa, WCCb, hst, h0cw, out,
        (i-2)*TCC, r0 ? TCC : 0, r1 ? TCC : 0, g0n, g1n,
        g0a, g0out, g1a, g1b, g1out,
        WC0p, WC1p, bias0, bias1);
  }
}